// Round 2
// baseline (154.541 us; speedup 1.0000x reference)
//
#include <hip/hip_runtime.h>
#include <hip/hip_bf16.h>
#include <cstdint>

// Problem constants
#define BATCH 8192
#define IN_F  1024
#define OUT_F 1024
#define G_HRS 1e-6f
#define G_LRS 1e-3f
#define PAR_R 2.0f
#define LEVELS 15.0f   // 2^4 - 1

// workspace layout (bytes)
#define WS_MM    0
#define WS_VEFF  4096
#define WS_VID   8192
#define WS_CORR  16384                    // 32 KB
#define WS_BT    65536                    // 2 MB bf16 W_effT
#define WS_ABF   (65536 + 2097152)        // 16 MB bf16 x
#define WS_NEED_FULL  (WS_ABF + (size_t)BATCH * IN_F * 2)
#define WS_NEED_MIN   ((size_t)WS_ABF)

// ---------- helpers ----------
__device__ __forceinline__ unsigned short f2bf(float f) {
    union { float f; unsigned int i; } v; v.f = f;
    unsigned int u = v.i;
    unsigned int r = (u + 0x7FFFu + ((u >> 16) & 1u)) >> 16;  // RNE
    return (unsigned short)r;
}
__device__ __forceinline__ unsigned int fmap(float f) {
    union { float f; unsigned int u; } v; v.f = f;
    return (v.u & 0x80000000u) ? ~v.u : (v.u | 0x80000000u);
}
__device__ __forceinline__ float funmap(unsigned int m) {
    union { unsigned int u; float f; } v;
    v.u = (m & 0x80000000u) ? (m & 0x7FFFFFFFu) : ~m;
    return v.f;
}
__device__ __forceinline__ float quant_g(float wv, float wmin, float inv_range) {
    float t = (wv - wmin) * inv_range;                    // [0,1]
    float step = (G_LRS - G_HRS) / LEVELS;
    return rintf(t * LEVELS) * step + G_HRS;              // rintf = half-to-even = jnp.round
}

// ---------- K0: init min/max slots ----------
__global__ void kinit(unsigned int* mm) {
    if (threadIdx.x == 0) { mm[0] = 0u; mm[1] = 0xFFFFFFFFu; }  // max-slot, min-slot
}

// ---------- K1: global min/max over weight (1M f32) ----------
__global__ void kminmax(const float* __restrict__ w, unsigned int* mm) {
    int tid = blockIdx.x * blockDim.x + threadIdx.x;
    int stride = gridDim.x * blockDim.x;
    float lo = 1e30f, hi = -1e30f;
    const float4* w4 = (const float4*)w;
    const int n4 = (IN_F * OUT_F) / 4;
    for (int i = tid; i < n4; i += stride) {
        float4 q = w4[i];
        lo = fminf(lo, fminf(fminf(q.x, q.y), fminf(q.z, q.w)));
        hi = fmaxf(hi, fmaxf(fmaxf(q.x, q.y), fmaxf(q.z, q.w)));
    }
#pragma unroll
    for (int m = 1; m < 64; m <<= 1) {
        lo = fminf(lo, __shfl_xor(lo, m, 64));
        hi = fmaxf(hi, __shfl_xor(hi, m, 64));
    }
    if ((threadIdx.x & 63) == 0) {
        atomicMax(&mm[0], fmap(hi));
        atomicMin(&mm[1], fmap(lo));
    }
}

// ---------- K2a: build W_effT [OUT_F][IN_F] bf16 ----------
// W_effT[n][k] = (G_eff(k,n) - bcoef) / acoef   (unmapping folded into B)
__global__ void kbuild(const float* __restrict__ w, const unsigned int* __restrict__ mm,
                       unsigned short* __restrict__ bt) {
    float wmax = funmap(mm[0]), wmin = funmap(mm[1]);
    float inv_range = 1.0f / (wmax - wmin);
    float acoef = (G_LRS - G_HRS) * inv_range;
    float bcoef = G_HRS - acoef * wmin;
    float inva = 1.0f / acoef;
    int n = blockIdx.x;
    int k0 = threadIdx.x * 4;                              // 256 thr * 4 = 1024 = IN_F
    float4 q = *(const float4*)&w[n * IN_F + k0];          // weight[n][k]; Wt[k][n] = weight[n][k]
    float wv[4] = { q.x, q.y, q.z, q.w };
    unsigned short o[4];
#pragma unroll
    for (int j = 0; j < 4; j++) {
        int k = k0 + j;
        float g = quant_g(wv[j], wmin, inv_range);
        float r = PAR_R * ((float)(n + 1) + (float)(IN_F - k));
        float ge = 1.0f / (1.0f / g + r);
        o[j] = f2bf((ge - bcoef) * inva);
    }
    uint2 ov;
    ov.x = (unsigned int)o[0] | ((unsigned int)o[1] << 16);
    ov.y = (unsigned int)o[2] | ((unsigned int)o[3] << 16);
    *(uint2*)&bt[n * IN_F + k0] = ov;
}

// ---------- K2b: v_eff[k] = sum_n G_eff(k,n), v_id[k] = sum_n G(k,n) ----------
__global__ void kvec(const float* __restrict__ w, const unsigned int* __restrict__ mm,
                     float* __restrict__ veff, float* __restrict__ vid) {
    float wmax = funmap(mm[0]), wmin = funmap(mm[1]);
    float inv_range = 1.0f / (wmax - wmin);
    int k = blockIdx.x;
    float se = 0.f, si = 0.f;
    for (int n = threadIdx.x; n < OUT_F; n += blockDim.x) {
        float g = quant_g(w[n * IN_F + k], wmin, inv_range);
        float r = PAR_R * ((float)(n + 1) + (float)(IN_F - k));
        se += 1.0f / (1.0f / g + r);
        si += g;
    }
#pragma unroll
    for (int m = 1; m < 64; m <<= 1) {
        se += __shfl_xor(se, m, 64);
        si += __shfl_xor(si, m, 64);
    }
    __shared__ float red[8];
    int wv = threadIdx.x >> 6, ln = threadIdx.x & 63;
    if (ln == 0) { red[wv] = se; red[4 + wv] = si; }
    __syncthreads();
    if (threadIdx.x == 0) {
        veff[k] = red[0] + red[1] + red[2] + red[3];
        vid[k]  = red[4] + red[5] + red[6] + red[7];
    }
}

// ---------- K3: corr[row] = (x.v_eff)/(x.v_id); optionally emit bf16 copy of x ----------
__global__ void kcorr(const float* __restrict__ x, const float* __restrict__ veff,
                      const float* __restrict__ vid, float* __restrict__ corr,
                      unsigned short* __restrict__ abf) {
    int row = blockIdx.x;
    int k0 = threadIdx.x * 4;                              // 256 thr * 4 = 1024
    float4 q = *(const float4*)&x[(size_t)row * IN_F + k0];
    if (abf) {
        uint2 ov;
        ov.x = (unsigned int)f2bf(q.x) | ((unsigned int)f2bf(q.y) << 16);
        ov.y = (unsigned int)f2bf(q.z) | ((unsigned int)f2bf(q.w) << 16);
        *(uint2*)&abf[(size_t)row * IN_F + k0] = ov;
    }
    float se = q.x * veff[k0] + q.y * veff[k0 + 1] + q.z * veff[k0 + 2] + q.w * veff[k0 + 3];
    float si = q.x * vid[k0]  + q.y * vid[k0 + 1]  + q.z * vid[k0 + 2]  + q.w * vid[k0 + 3];
#pragma unroll
    for (int m = 1; m < 64; m <<= 1) {
        se += __shfl_xor(se, m, 64);
        si += __shfl_xor(si, m, 64);
    }
    __shared__ float red[8];
    int wv = threadIdx.x >> 6, ln = threadIdx.x & 63;
    if (ln == 0) { red[wv] = se; red[4 + wv] = si; }
    __syncthreads();
    if (threadIdx.x == 0)
        corr[row] = (red[0] + red[1] + red[2] + red[3]) / (red[4] + red[5] + red[6] + red[7]);
}

// ---------- K4: GEMM out = x @ W_eff + bias*corr ----------
typedef __attribute__((ext_vector_type(8))) short bf16x8;
typedef __attribute__((ext_vector_type(4))) float f32x4;

#define GLD_LDS16(g, l) \
    __builtin_amdgcn_global_load_lds((const __attribute__((address_space(1))) void*)(g), \
                                     (__attribute__((address_space(3))) void*)(l), 16, 0, 0)

// CONVA=false: A pre-converted bf16 in ws (Abf). CONVA=true: convert f32 x during staging.
template <bool CONVA>
__global__ __launch_bounds__(256) void kgemm(
    const float* __restrict__ Af32,          // x [8192,1024] f32
    const unsigned short* __restrict__ Abf,  // x bf16 copy (or null)
    const unsigned short* __restrict__ Bt,   // W_effT [1024,1024] bf16
    const float* __restrict__ bias,          // [1024] f32
    const float* __restrict__ corr,          // [8192] f32
    float* __restrict__ out)                 // [8192,1024] f32
{
    __shared__ unsigned short As[128 * 32];
    __shared__ unsigned short Bs[128 * 32];
    const int tid = threadIdx.x;
    const int bm = blockIdx.x * 128;
    const int bn = blockIdx.y * 128;
    const int wave = tid >> 6, lane = tid & 63;
    const int wmL = (wave >> 1) * 64;
    const int wnL = (wave & 1) * 64;
    const int fr = lane & 15;
    const int fk = (lane >> 4) * 8;
    const int quad = lane >> 4;

    f32x4 acc[4][4] = {};

    // chunk c (0..511): row c>>2, 8-elem k-piece c&3; LDS dest = base + lane*16B (wave-uniform rule)
    const int c0 = tid, c1 = tid + 256;
    const unsigned short* gB0 = Bt + (size_t)(bn + (c0 >> 2)) * IN_F + ((c0 & 3) << 3);
    const unsigned short* gB1 = Bt + (size_t)(bn + (c1 >> 2)) * IN_F + ((c1 & 3) << 3);
    const unsigned short* gA0 = nullptr; const unsigned short* gA1 = nullptr;
    const float* fA0 = nullptr; const float* fA1 = nullptr;
    if (CONVA) {
        fA0 = Af32 + (size_t)(bm + (c0 >> 2)) * IN_F + ((c0 & 3) << 3);
        fA1 = Af32 + (size_t)(bm + (c1 >> 2)) * IN_F + ((c1 & 3) << 3);
    } else {
        gA0 = Abf + (size_t)(bm + (c0 >> 2)) * IN_F + ((c0 & 3) << 3);
        gA1 = Abf + (size_t)(bm + (c1 >> 2)) * IN_F + ((c1 & 3) << 3);
    }

    for (int kb = 0; kb < IN_F; kb += 32) {
        uint2 cv0, cv1;
        if (CONVA) {
            float4 p0 = *(const float4*)(fA0 + kb);
            float4 p1 = *(const float4*)(fA0 + kb + 4);
            float4 p2 = *(const float4*)(fA1 + kb);
            float4 p3 = *(const float4*)(fA1 + kb + 4);
            cv0.x = (unsigned int)f2bf(p0.x) | ((unsigned int)f2bf(p0.y) << 16);
            cv0.y = (unsigned int)f2bf(p0.z) | ((unsigned int)f2bf(p0.w) << 16);
            uint2 cv0b; cv0b.x = (unsigned int)f2bf(p1.x) | ((unsigned int)f2bf(p1.y) << 16);
            cv0b.y = (unsigned int)f2bf(p1.z) | ((unsigned int)f2bf(p1.w) << 16);
            uint2 cv1a; cv1a.x = (unsigned int)f2bf(p2.x) | ((unsigned int)f2bf(p2.y) << 16);
            cv1a.y = (unsigned int)f2bf(p2.z) | ((unsigned int)f2bf(p2.w) << 16);
            uint2 cv1b; cv1b.x = (unsigned int)f2bf(p3.x) | ((unsigned int)f2bf(p3.y) << 16);
            cv1b.y = (unsigned int)f2bf(p3.z) | ((unsigned int)f2bf(p3.w) << 16);
            __syncthreads();
            *(uint4*)&As[c0 * 8] = make_uint4(cv0.x, cv0.y, cv0b.x, cv0b.y);
            *(uint4*)&As[c1 * 8] = make_uint4(cv1a.x, cv1a.y, cv1b.x, cv1b.y);
            GLD_LDS16(gB0 + kb, &Bs[c0 * 8]);
            GLD_LDS16(gB1 + kb, &Bs[c1 * 8]);
        } else {
            __syncthreads();
            GLD_LDS16(gA0 + kb, &As[c0 * 8]);
            GLD_LDS16(gA1 + kb, &As[c1 * 8]);
            GLD_LDS16(gB0 + kb, &Bs[c0 * 8]);
            GLD_LDS16(gB1 + kb, &Bs[c1 * 8]);
        }
        __syncthreads();

        bf16x8 af[4], bfv[4];
#pragma unroll
        for (int mt = 0; mt < 4; mt++)
            af[mt] = *(const bf16x8*)&As[(wmL + mt * 16 + fr) * 32 + fk];
#pragma unroll
        for (int nt = 0; nt < 4; nt++)
            bfv[nt] = *(const bf16x8*)&Bs[(wnL + nt * 16 + fr) * 32 + fk];
#pragma unroll
        for (int mt = 0; mt < 4; mt++)
#pragma unroll
            for (int nt = 0; nt < 4; nt++)
                acc[mt][nt] = __builtin_amdgcn_mfma_f32_16x16x32_bf16(af[mt], bfv[nt], acc[mt][nt], 0, 0, 0);
    }

    // epilogue: out[r][c] = acc + bias[c]*corr[r]  (C/D: col=lane&15, row=quad*4+reg)
#pragma unroll
    for (int nt = 0; nt < 4; nt++) {
        int gc = bn + wnL + nt * 16 + fr;
        float bv = bias[gc];
#pragma unroll
        for (int mt = 0; mt < 4; mt++) {
#pragma unroll
            for (int r = 0; r < 4; r++) {
                int gr = bm + wmL + mt * 16 + quad * 4 + r;
                out[(size_t)gr * OUT_F + gc] = acc[mt][nt][r] + bv * corr[gr];
            }
        }
    }
}

// ---------- launch ----------
extern "C" void kernel_launch(void* const* d_in, const int* in_sizes, int n_in,
                              void* d_out, int out_size, void* d_ws, size_t ws_size,
                              hipStream_t stream) {
    const float* x    = (const float*)d_in[0];   // [8192,1024] f32
    const float* w    = (const float*)d_in[1];   // [1024,1024] f32 (out,in)
    const float* bias = (const float*)d_in[2];   // [1024] f32
    float* out = (float*)d_out;

    char* ws = (char*)d_ws;
    unsigned int* mm   = (unsigned int*)(ws + WS_MM);
    float* veff        = (float*)(ws + WS_VEFF);
    float* vid         = (float*)(ws + WS_VID);
    float* corr        = (float*)(ws + WS_CORR);
    unsigned short* bt = (unsigned short*)(ws + WS_BT);
    unsigned short* abf = (unsigned short*)(ws + WS_ABF);

    bool full = ws_size >= WS_NEED_FULL;

    kinit<<<1, 64, 0, stream>>>(mm);
    kminmax<<<256, 256, 0, stream>>>(w, mm);
    kbuild<<<OUT_F, 256, 0, stream>>>(w, mm, bt);
    kvec<<<IN_F, 256, 0, stream>>>(w, mm, veff, vid);
    kcorr<<<BATCH, 256, 0, stream>>>(x, veff, vid, corr, full ? abf : nullptr);
    if (full)
        kgemm<false><<<dim3(BATCH / 128, OUT_F / 128), 256, 0, stream>>>(x, abf, bt, bias, corr, out);
    else
        kgemm<true><<<dim3(BATCH / 128, OUT_F / 128), 256, 0, stream>>>(x, nullptr, bt, bias, corr, out);
}

// Round 3
// 148.091 us; speedup vs baseline: 1.0436x; 1.0436x over previous
//
#include <hip/hip_runtime.h>
#include <hip/hip_bf16.h>
#include <cstdint>

// Problem constants
#define BATCH 8192
#define IN_F  1024
#define OUT_F 1024
#define G_HRS 1e-6f
#define G_LRS 1e-3f
#define PAR_R 2.0f
#define LEVELS 15.0f   // 2^4 - 1

// workspace layout (bytes)
#define WS_PMIN  0                        // 256 f32 per-block min partials
#define WS_PMAX  1024                     // 256 f32 per-block max partials
#define WS_VEFF  4096                     // 1024 f32
#define WS_VID   8192                     // 1024 f32
#define WS_CORR  16384                    // 32 KB (8192 f32)
#define WS_BT    65536                    // 2 MB bf16 W_effT
#define WS_ABF   (65536 + 2097152)        // 16 MB bf16 x
#define WS_NEED_FULL  ((size_t)WS_ABF + (size_t)BATCH * IN_F * 2)

// ---------- helpers ----------
__device__ __forceinline__ unsigned short f2bf(float f) {
    union { float f; unsigned int i; } v; v.f = f;
    unsigned int u = v.i;
    unsigned int r = (u + 0x7FFFu + ((u >> 16) & 1u)) >> 16;  // RNE
    return (unsigned short)r;
}
__device__ __forceinline__ float quant_g(float wv, float wmin, float inv_range) {
    float t = (wv - wmin) * inv_range;                    // [0,1]
    float step = (G_LRS - G_HRS) / LEVELS;
    return rintf(t * LEVELS) * step + G_HRS;              // rintf = RNE = jnp.round
}

// ---------- K1: per-block min/max partials over weight; block 0 zeros veff/vid ----------
__global__ void kprep(const float* __restrict__ w, float* __restrict__ pmin, float* __restrict__ pmax,
                      float* __restrict__ veff, float* __restrict__ vid) {
    int tid = blockIdx.x * blockDim.x + threadIdx.x;
    float lo = 1e30f, hi = -1e30f;
    const float4* w4 = (const float4*)w;
    const int n4 = (IN_F * OUT_F) / 4;                    // 262144
    for (int i = tid; i < n4; i += 256 * 256) {
        float4 q = w4[i];
        lo = fminf(lo, fminf(fminf(q.x, q.y), fminf(q.z, q.w)));
        hi = fmaxf(hi, fmaxf(fmaxf(q.x, q.y), fmaxf(q.z, q.w)));
    }
#pragma unroll
    for (int m = 1; m < 64; m <<= 1) {
        lo = fminf(lo, __shfl_xor(lo, m, 64));
        hi = fmaxf(hi, __shfl_xor(hi, m, 64));
    }
    __shared__ float slo[4], shi[4];
    int wv = threadIdx.x >> 6, ln = threadIdx.x & 63;
    if (ln == 0) { slo[wv] = lo; shi[wv] = hi; }
    __syncthreads();
    if (threadIdx.x == 0) {
        pmin[blockIdx.x] = fminf(fminf(slo[0], slo[1]), fminf(slo[2], slo[3]));
        pmax[blockIdx.x] = fmaxf(fmaxf(shi[0], shi[1]), fmaxf(shi[2], shi[3]));
    }
    if (blockIdx.x == 0) {                                 // zero accumulators for K2's atomics
        float4 z = make_float4(0.f, 0.f, 0.f, 0.f);
        ((float4*)veff)[threadIdx.x] = z;                  // 256 * 4 = 1024
        ((float4*)vid)[threadIdx.x]  = z;
    }
}

// ---------- K2: build W_effT bf16 + accumulate veff/vid (register accumulation, coalesced) ----------
// block b handles weight rows n = 4b..4b+3; thread t owns k = 4t..4t+3 for all 4 rows.
__global__ void kbuildvec(const float* __restrict__ w, const float* __restrict__ pmin,
                          const float* __restrict__ pmax, unsigned short* __restrict__ bt,
                          float* __restrict__ veff, float* __restrict__ vid) {
    // reduce the 256 min/max partials (every block does this; ~1024 flops)
    float lo = pmin[threadIdx.x], hi = pmax[threadIdx.x];
#pragma unroll
    for (int m = 1; m < 64; m <<= 1) {
        lo = fminf(lo, __shfl_xor(lo, m, 64));
        hi = fmaxf(hi, __shfl_xor(hi, m, 64));
    }
    __shared__ float slo[4], shi[4];
    int wv = threadIdx.x >> 6, ln = threadIdx.x & 63;
    if (ln == 0) { slo[wv] = lo; shi[wv] = hi; }
    __syncthreads();
    float wmin = fminf(fminf(slo[0], slo[1]), fminf(slo[2], slo[3]));
    float wmax = fmaxf(fmaxf(shi[0], shi[1]), fmaxf(shi[2], shi[3]));

    float inv_range = 1.0f / (wmax - wmin);
    float acoef = (G_LRS - G_HRS) * inv_range;
    float bcoef = G_HRS - acoef * wmin;
    float inva = 1.0f / acoef;

    int k0 = threadIdx.x * 4;
    float se[4] = {0.f, 0.f, 0.f, 0.f}, si[4] = {0.f, 0.f, 0.f, 0.f};
#pragma unroll
    for (int rr = 0; rr < 4; rr++) {
        int n = blockIdx.x * 4 + rr;
        float4 q = *(const float4*)&w[(size_t)n * IN_F + k0];
        float wvv[4] = { q.x, q.y, q.z, q.w };
        unsigned short o[4];
#pragma unroll
        for (int j = 0; j < 4; j++) {
            int k = k0 + j;
            float g = quant_g(wvv[j], wmin, inv_range);
            float r = PAR_R * ((float)(n + 1) + (float)(IN_F - k));
            float ge = 1.0f / (1.0f / g + r);
            o[j] = f2bf((ge - bcoef) * inva);
            se[j] += ge;
            si[j] += g;
        }
        uint2 ov;
        ov.x = (unsigned int)o[0] | ((unsigned int)o[1] << 16);
        ov.y = (unsigned int)o[2] | ((unsigned int)o[3] << 16);
        *(uint2*)&bt[(size_t)n * IN_F + k0] = ov;
    }
#pragma unroll
    for (int j = 0; j < 4; j++) {
        atomicAdd(&veff[k0 + j], se[j]);
        atomicAdd(&vid[k0 + j], si[j]);
    }
}

// ---------- K3: corr[row] = (x.v_eff)/(x.v_id); emit bf16 copy of x ----------
__global__ void kcorr(const float* __restrict__ x, const float* __restrict__ veff,
                      const float* __restrict__ vid, float* __restrict__ corr,
                      unsigned short* __restrict__ abf) {
    int row = blockIdx.x;
    int k0 = threadIdx.x * 4;
    float4 q = *(const float4*)&x[(size_t)row * IN_F + k0];
    if (abf) {
        uint2 ov;
        ov.x = (unsigned int)f2bf(q.x) | ((unsigned int)f2bf(q.y) << 16);
        ov.y = (unsigned int)f2bf(q.z) | ((unsigned int)f2bf(q.w) << 16);
        *(uint2*)&abf[(size_t)row * IN_F + k0] = ov;
    }
    float4 ve = *(const float4*)&veff[k0];
    float4 vi = *(const float4*)&vid[k0];
    float se = q.x * ve.x + q.y * ve.y + q.z * ve.z + q.w * ve.w;
    float si = q.x * vi.x + q.y * vi.y + q.z * vi.z + q.w * vi.w;
#pragma unroll
    for (int m = 1; m < 64; m <<= 1) {
        se += __shfl_xor(se, m, 64);
        si += __shfl_xor(si, m, 64);
    }
    __shared__ float red[8];
    int wv = threadIdx.x >> 6, ln = threadIdx.x & 63;
    if (ln == 0) { red[wv] = se; red[4 + wv] = si; }
    __syncthreads();
    if (threadIdx.x == 0)
        corr[row] = (red[0] + red[1] + red[2] + red[3]) / (red[4] + red[5] + red[6] + red[7]);
}

// ---------- K4: GEMM out = x @ W_eff + bias*corr ----------
typedef __attribute__((ext_vector_type(8))) short bf16x8;
typedef __attribute__((ext_vector_type(4))) float f32x4;

#define GLD_LDS16(g, l) \
    __builtin_amdgcn_global_load_lds((const __attribute__((address_space(1))) void*)(g), \
                                     (__attribute__((address_space(3))) void*)(l), 16, 0, 0)

// CONVA=false: A pre-converted bf16 in ws. CONVA=true: convert f32 x during staging (fallback).
template <bool CONVA>
__global__ __launch_bounds__(256) void kgemm(
    const float* __restrict__ Af32,
    const unsigned short* __restrict__ Abf,
    const unsigned short* __restrict__ Bt,   // W_effT [1024,1024] bf16
    const float* __restrict__ bias,          // [1024] f32
    const float* __restrict__ corr,          // [8192] f32
    float* __restrict__ out)                 // [8192,1024] f32
{
    __shared__ unsigned short As[128 * 32];
    __shared__ unsigned short Bs[128 * 32];
    const int tid = threadIdx.x;
    // grid = (N-blocks, M-blocks): consecutive blocks share the A-tile -> A from HBM ~once,
    // B (2 MB total) stays L2-resident across its 64 re-reads.
    const int bn = blockIdx.x * 128;
    const int bm = blockIdx.y * 128;
    const int wave = tid >> 6, lane = tid & 63;
    const int wmL = (wave >> 1) * 64;
    const int wnL = (wave & 1) * 64;
    const int fr = lane & 15;
    const int fk = (lane >> 4) * 8;
    const int quad = lane >> 4;

    f32x4 acc[4][4] = {};

    // chunk c (0..511): row c>>2, 8-elem k-piece c&3; LDS dest = base + lane*16B (wave-uniform rule)
    const int c0 = tid, c1 = tid + 256;
    const unsigned short* gB0 = Bt + (size_t)(bn + (c0 >> 2)) * IN_F + ((c0 & 3) << 3);
    const unsigned short* gB1 = Bt + (size_t)(bn + (c1 >> 2)) * IN_F + ((c1 & 3) << 3);
    const unsigned short* gA0 = nullptr; const unsigned short* gA1 = nullptr;
    const float* fA0 = nullptr; const float* fA1 = nullptr;
    if (CONVA) {
        fA0 = Af32 + (size_t)(bm + (c0 >> 2)) * IN_F + ((c0 & 3) << 3);
        fA1 = Af32 + (size_t)(bm + (c1 >> 2)) * IN_F + ((c1 & 3) << 3);
    } else {
        gA0 = Abf + (size_t)(bm + (c0 >> 2)) * IN_F + ((c0 & 3) << 3);
        gA1 = Abf + (size_t)(bm + (c1 >> 2)) * IN_F + ((c1 & 3) << 3);
    }

    for (int kb = 0; kb < IN_F; kb += 32) {
        if (CONVA) {
            float4 p0 = *(const float4*)(fA0 + kb);
            float4 p1 = *(const float4*)(fA0 + kb + 4);
            float4 p2 = *(const float4*)(fA1 + kb);
            float4 p3 = *(const float4*)(fA1 + kb + 4);
            uint4 u0 = make_uint4(
                (unsigned int)f2bf(p0.x) | ((unsigned int)f2bf(p0.y) << 16),
                (unsigned int)f2bf(p0.z) | ((unsigned int)f2bf(p0.w) << 16),
                (unsigned int)f2bf(p1.x) | ((unsigned int)f2bf(p1.y) << 16),
                (unsigned int)f2bf(p1.z) | ((unsigned int)f2bf(p1.w) << 16));
            uint4 u1 = make_uint4(
                (unsigned int)f2bf(p2.x) | ((unsigned int)f2bf(p2.y) << 16),
                (unsigned int)f2bf(p2.z) | ((unsigned int)f2bf(p2.w) << 16),
                (unsigned int)f2bf(p3.x) | ((unsigned int)f2bf(p3.y) << 16),
                (unsigned int)f2bf(p3.z) | ((unsigned int)f2bf(p3.w) << 16));
            __syncthreads();
            *(uint4*)&As[c0 * 8] = u0;
            *(uint4*)&As[c1 * 8] = u1;
            GLD_LDS16(gB0 + kb, &Bs[c0 * 8]);
            GLD_LDS16(gB1 + kb, &Bs[c1 * 8]);
        } else {
            __syncthreads();
            GLD_LDS16(gA0 + kb, &As[c0 * 8]);
            GLD_LDS16(gA1 + kb, &As[c1 * 8]);
            GLD_LDS16(gB0 + kb, &Bs[c0 * 8]);
            GLD_LDS16(gB1 + kb, &Bs[c1 * 8]);
        }
        __syncthreads();

        bf16x8 af[4], bfv[4];
#pragma unroll
        for (int mt = 0; mt < 4; mt++)
            af[mt] = *(const bf16x8*)&As[(wmL + mt * 16 + fr) * 32 + fk];
#pragma unroll
        for (int nt = 0; nt < 4; nt++)
            bfv[nt] = *(const bf16x8*)&Bs[(wnL + nt * 16 + fr) * 32 + fk];
#pragma unroll
        for (int mt = 0; mt < 4; mt++)
#pragma unroll
            for (int nt = 0; nt < 4; nt++)
                acc[mt][nt] = __builtin_amdgcn_mfma_f32_16x16x32_bf16(af[mt], bfv[nt], acc[mt][nt], 0, 0, 0);
    }

    // epilogue: out[r][c] = acc + bias[c]*corr[r]  (C/D: col=lane&15, row=quad*4+reg)
#pragma unroll
    for (int nt = 0; nt < 4; nt++) {
        int gc = bn + wnL + nt * 16 + fr;
        float bv = bias[gc];
#pragma unroll
        for (int mt = 0; mt < 4; mt++) {
#pragma unroll
            for (int r = 0; r < 4; r++) {
                int gr = bm + wmL + mt * 16 + quad * 4 + r;
                out[(size_t)gr * OUT_F + gc] = acc[mt][nt][r] + bv * corr[gr];
            }
        }
    }
}

// ---------- launch ----------
extern "C" void kernel_launch(void* const* d_in, const int* in_sizes, int n_in,
                              void* d_out, int out_size, void* d_ws, size_t ws_size,
                              hipStream_t stream) {
    const float* x    = (const float*)d_in[0];   // [8192,1024] f32
    const float* w    = (const float*)d_in[1];   // [1024,1024] f32 (out,in)
    const float* bias = (const float*)d_in[2];   // [1024] f32
    float* out = (float*)d_out;

    char* ws = (char*)d_ws;
    float* pmin        = (float*)(ws + WS_PMIN);
    float* pmax        = (float*)(ws + WS_PMAX);
    float* veff        = (float*)(ws + WS_VEFF);
    float* vid         = (float*)(ws + WS_VID);
    float* corr        = (float*)(ws + WS_CORR);
    unsigned short* bt = (unsigned short*)(ws + WS_BT);
    unsigned short* abf = (unsigned short*)(ws + WS_ABF);

    bool full = ws_size >= WS_NEED_FULL;

    kprep<<<256, 256, 0, stream>>>(w, pmin, pmax, veff, vid);
    kbuildvec<<<OUT_F / 4, 256, 0, stream>>>(w, pmin, pmax, bt, veff, vid);
    kcorr<<<BATCH, 256, 0, stream>>>(x, veff, vid, corr, full ? abf : nullptr);
    if (full)
        kgemm<false><<<dim3(OUT_F / 128, BATCH / 128), 256, 0, stream>>>(x, abf, bt, bias, corr, out);
    else
        kgemm<true><<<dim3(OUT_F / 128, BATCH / 128), 256, 0, stream>>>(x, nullptr, bt, bias, corr, out);
}